// Round 10
// baseline (590.628 us; speedup 1.0000x reference)
//
#include <hip/hip_runtime.h>
#include <hip/hip_bf16.h>
#include <math.h>

// Problem constants
#define DDIM 1024
#define NH   16
#define LTOK 512
#define NBATCH 16

typedef unsigned short u16;
typedef unsigned short u16x8 __attribute__((ext_vector_type(8)));
typedef unsigned short u16x4 __attribute__((ext_vector_type(4)));
typedef __bf16 bf16x8 __attribute__((ext_vector_type(8)));
typedef float f32x4 __attribute__((ext_vector_type(4)));

typedef __attribute__((address_space(1))) void as1_void;
typedef __attribute__((address_space(3))) void as3_void;

__device__ __forceinline__ void llds16(const u16* g, u16* l) {
    // async 16B global->LDS DMA; LDS dest = wave-uniform base + lane*16B
    __builtin_amdgcn_global_load_lds((as1_void*)g, (as3_void*)l, 16, 0, 0);
}

__device__ __forceinline__ float bf2f(u16 u) {
    unsigned v = ((unsigned)u) << 16;
    float f; __builtin_memcpy(&f, &v, 4); return f;
}
__device__ __forceinline__ u16 f2bf(float f) {
    unsigned u; __builtin_memcpy(&u, &f, 4);
    u += 0x7fffu + ((u >> 16) & 1u);   // RNE
    return (u16)(u >> 16);
}

// One GEMM operand set:  C = act(scale*(A@B^T)+bias).
// If VTp != nullptr, output columns >= vtcol0 are per-head V projections and
// are written TRANSPOSED to VTp[((row/512)*NH + h)*64 + dd][row%512].
struct GemmOp {
    const u16* A; const u16* B; u16* C; float* Cf; const float* bias;
    u16* VTp;
    long sA1, sA2, sB1, sB2, sC1, sC2;
    int lda, ldb, ldc, M, N, K, zdiv, flags, nblk, vtcol0;
    float scale;
};

// ---------------------------------------------------------------------------
// Shared epilogue fragment-store (C^T convention: lane holds 4 consecutive
// output columns per fragment; V-column tiles redirect transposed to VT).
// ---------------------------------------------------------------------------
__device__ __forceinline__ void store_frag(
    const GemmOp& o, u16* Cb, float* Cfb, long row, int col, f32x4 a)
{
    f32x4 bv = o.bias ? *(const f32x4*)(o.bias + col)
                      : (f32x4){0.f, 0.f, 0.f, 0.f};
    f32x4 v4;
#pragma unroll
    for (int r = 0; r < 4; r++) {
        float v = a[r] * o.scale + bv[r];
        if (o.flags & 1)
            v = 0.5f * v * (1.f + erff(v * 0.70710678118654752f));
        v4[r] = v;
    }
    if (o.VTp && col >= o.vtcol0) {
        const int dv  = col - o.vtcol0;          // head h = dv>>6
        const long bh = (row >> 9) * NH + (dv >> 6);
        const int tok = (int)(row & (LTOK - 1));
        u16* vp = o.VTp + (bh * 64 + (dv & 63)) * LTOK + tok;
#pragma unroll
        for (int r = 0; r < 4; r++)
            vp[(long)r * LTOK] = f2bf(v4[r]);
    } else if (Cfb) {
        *(f32x4*)(Cfb + row * o.ldc + col) = v4;
    } else {
        u16x4 ov;
#pragma unroll
        for (int r = 0; r < 4; r++) ov[r] = f2bf(v4[r]);
        *(u16x4*)(Cb + row * o.ldc + col) = ov;
    }
}

// ---------------------------------------------------------------------------
// 8-phase 256x256 GEMM (T3+T4+T5+T2 co-designed; guide §5 template adapted).
// 512 threads = 8 waves (2M x 4N); per-wave output 128x64 held as acc[8][4]
// with INTERLEAVED ownership row = (mq>>2)*128 + (mq&3)*32 + wm2*16 + l16,
// col = (nq>>1)*128 + (nq&1)*64 + wn4*16 + quad*4 -- so each phase's LDS
// fragment reads touch ONE wave-uniform half-tile:
//   P0: A-half0 (H0) + B-half0 (H2); P1: B-half1 (H3); P2: A-half1 (H1); P3: -
// Per K-tile (BK=64, 2 MFMA k-steps), 4 phases x 16 MFMA.  Staging: 8
// global_load_lds/thread/K-tile, issued one half-tile per phase in the SAME
// consumption order (H0,H2,H3,H1) one tile ahead -> every needed half-tile
// has exactly 4 younger loads outstanding at its wait point => counted
// s_waitcnt vmcnt(4) (never 0 mid-loop, T4); raw s_barrier publishes the
// landed LDS writes (no __syncthreads -> no compiler vmcnt(0) drain).
// vmcnt counting is conservative-safe under spills (extra younger ops only
// force MORE of the needed oldest loads to complete).
// LDS: linear dest + XOR-swizzled (16B-granular, unit ^= row&7) global source
// and identically swizzled ds_read cols -> 2-way banked = free (r9: 0
// conflicts).  setprio(1) around each MFMA cluster (T5, pays at 8-phase).
// M,N multiples of 256; K multiple of 128.
// ---------------------------------------------------------------------------
__global__ __launch_bounds__(512, 2) void gemm8_kernel(GemmOp o1, GemmOp o2)
{
    constexpr int BUFE = 256 * 64;                 // u16 elems per buffer
    __shared__ __align__(16) u16 As[2 * BUFE];     // 64 KB
    __shared__ __align__(16) u16 Bs[2 * BUFE];     // 64 KB

    const bool second = (int)blockIdx.x >= o1.nblk;
    const GemmOp& o = second ? o2 : o1;
    int bidx = blockIdx.x - (second ? o1.nblk : 0);

    const int tilesN = o.N >> 8;
    const int tilesM = o.M >> 8;
    const int tiles  = tilesM * tilesN;
    const int z = bidx / tiles;
    const int t = bidx - z * tiles;
    const int zb = z / o.zdiv, zh = z - zb * o.zdiv;

    int tm, tn;
    if ((tilesM & 7) == 0) {
        const int xcd = t & 7, idx = t >> 3;
        const int mg  = tilesM >> 3;
        tm = ((idx % mg) << 3) | xcd;
        tn = idx / mg;
    } else {
        tm = t / tilesN;
        tn = t - tm * tilesN;
    }
    const int m0 = tm << 8, n0 = tn << 8;

    const u16* Ab = o.A + (long)zb * o.sA1 + (long)zh * o.sA2;
    const u16* Bb = o.B + (long)zb * o.sB1 + (long)zh * o.sB2;
    u16*   Cb  = o.C  ? o.C  + (long)zb * o.sC1 + (long)zh * o.sC2 : nullptr;
    float* Cfb = o.Cf ? o.Cf + (long)zb * o.sC1 + (long)zh * o.sC2 : nullptr;

    const int tid  = threadIdx.x;
    const int lane = tid & 63;
    const int wave = tid >> 6;
    const int wm2 = wave >> 2, wn4 = wave & 3;     // 2M x 4N wave grid
    const int quad = lane >> 4, l16 = lane & 15;

    f32x4 acc[8][4];
#pragma unroll
    for (int i = 0; i < 8; i++)
#pragma unroll
        for (int j = 0; j < 4; j++) acc[i][j] = (f32x4){0.f, 0.f, 0.f, 0.f};

    // staging map: per half-tile (128 rows x 64 cols), thread loads 2x16B:
    //   load i: row = srow + i*64, swizzled col unit = sunit ^ (srow&7)
    const int srow  = tid >> 3;
    const int scol  = (((tid & 7) ^ (srow & 7)) << 3);
    const u16* gA = Ab + (long)(m0 + srow) * o.lda + scol;
    const u16* gB = Bb + (long)(n0 + srow) * o.ldb + scol;
    u16* lA = As + tid * 8;
    u16* lB = Bs + tid * 8;

    const long ldaL = o.lda, ldbL = o.ldb;
    auto SA = [&](int par, int k0, int hz) {        // stage A half-tile hz
        llds16(gA + (long)(hz * 128) * ldaL + k0,      lA + par * BUFE + hz * 8192);
        llds16(gA + (long)(hz * 128 + 64) * ldaL + k0, lA + par * BUFE + hz * 8192 + 4096);
    };
    auto SB = [&](int par, int k0, int hz) {        // stage B half-tile hz
        llds16(gB + (long)(hz * 128) * ldbL + k0,      lB + par * BUFE + hz * 8192);
        llds16(gB + (long)(hz * 128 + 64) * ldbL + k0, lB + par * BUFE + hz * 8192 + 4096);
    };

    // fragment-read swizzled col offsets (elems), ks = MFMA k-step 0/1
    const int c0 = ((quad)     ^ (l16 & 7)) << 3;
    const int c1 = ((4 + quad) ^ (l16 & 7)) << 3;
    const int arow0 = wm2 * 16 + l16;               // + (mq&3)*32 (+128 half1)
    const int brow0 = wn4 * 16 + l16;               // + (nq&1)*64 (+128 half1)

    bf16x8 af[4][2], b01[2][2], b23[2][2];

#define LD_A(Ac, mh) do { _Pragma("unroll") \
    for (int mq2 = 0; mq2 < 4; mq2++) { \
        const u16* p_ = (Ac) + ((mh) * 128 + mq2 * 32 + arow0) * 64; \
        af[mq2][0] = *(const bf16x8*)(p_ + c0); \
        af[mq2][1] = *(const bf16x8*)(p_ + c1); } } while (0)
#define LD_B(Bc, arr, nh) do { _Pragma("unroll") \
    for (int nq2 = 0; nq2 < 2; nq2++) { \
        const u16* p_ = (Bc) + ((nh) * 128 + nq2 * 64 + brow0) * 64; \
        arr[nq2][0] = *(const bf16x8*)(p_ + c0); \
        arr[nq2][1] = *(const bf16x8*)(p_ + c1); } } while (0)
#define MM(arr, mh, nh) do { \
    __builtin_amdgcn_s_setprio(1); \
    _Pragma("unroll") for (int mq2 = 0; mq2 < 4; mq2++) \
    _Pragma("unroll") for (int nq2 = 0; nq2 < 2; nq2++) \
    _Pragma("unroll") for (int ks = 0; ks < 2; ks++) \
        acc[(mh)*4 + mq2][(nh)*2 + nq2] = __builtin_amdgcn_mfma_f32_16x16x32_bf16( \
            arr[nq2][ks], af[mq2][ks], acc[(mh)*4 + mq2][(nh)*2 + nq2], 0, 0, 0); \
    __builtin_amdgcn_s_setprio(0); } while (0)

    // prologue: tile 0 in consumption order H0, H2, H3, H1
    SA(0, 0, 0); SB(0, 0, 0); SB(0, 0, 1); SA(0, 0, 1);

    const int NT = o.K >> 6;
    for (int k = 0; k < NT; k++) {
        const int par = k & 1, ip = par ^ 1;
        const u16* Ac = As + par * BUFE;
        const u16* Bc = Bs + par * BUFE;
        const int kn = (k + 1) << 6;
        const bool more = (k + 1 < NT);

        // ---- P0: consume H0 (A-half0) + H2 (B-half0) ----
        asm volatile("s_waitcnt vmcnt(4)" ::: "memory");
        __builtin_amdgcn_s_barrier();
        asm volatile("" ::: "memory");
        if (more) SA(ip, kn, 0);                       // issue H0'
        LD_A(Ac, 0);
        LD_B(Bc, b01, 0);
        MM(b01, 0, 0);

        // ---- P1: consume H3 (B-half1) ----
        if (more) asm volatile("s_waitcnt vmcnt(4)" ::: "memory");
        else      asm volatile("s_waitcnt vmcnt(2)" ::: "memory");
        __builtin_amdgcn_s_barrier();
        asm volatile("" ::: "memory");
        if (more) SB(ip, kn, 0);                       // issue H2'
        LD_B(Bc, b23, 1);
        MM(b23, 0, 1);

        // ---- P2: consume H1 (A-half1) ----
        if (more) asm volatile("s_waitcnt vmcnt(4)" ::: "memory");
        else      asm volatile("s_waitcnt vmcnt(0)" ::: "memory");
        __builtin_amdgcn_s_barrier();
        asm volatile("" ::: "memory");
        if (more) SB(ip, kn, 1);                       // issue H3'
        LD_A(Ac, 1);
        MM(b01, 1, 0);

        // ---- P3: register-only (af half1 + cached b23) ----
        if (more) SA(ip, kn, 1);                       // issue H1'
        MM(b23, 1, 1);
    }
#undef LD_A
#undef LD_B
#undef MM

    // epilogue: C^T fragments, interleaved ownership
#pragma unroll
    for (int mq = 0; mq < 8; mq++) {
        const long row = m0 + (mq >> 2) * 128 + (mq & 3) * 32 + wm2 * 16 + l16;
#pragma unroll
        for (int nq = 0; nq < 4; nq++) {
            const int col = n0 + (nq >> 1) * 128 + (nq & 1) * 64
                          + wn4 * 16 + quad * 4;
            store_frag(o, Cb, Cfb, row, col, acc[mq][nq]);
        }
    }
}

// ---------------------------------------------------------------------------
// Dual-op 128x128 MFMA GEMM (MODE1 2-phase dbuf) -- used for the small-grid
// launches (vis|int, out) where 256^2 blocks would starve the GPU.
// XOR swizzle (r9): staging source col and read col XORed with row-derived
// term -> bank-conflict-free (measured 0).  C^T epilogue via operand swap.
// ---------------------------------------------------------------------------
__global__ __launch_bounds__(256) void gemm_bt_kernel(GemmOp o1, GemmOp o2)
{
    constexpr int BUFE = 128 * 32;
    __shared__ __align__(16) u16 As[2 * BUFE];
    __shared__ __align__(16) u16 Bs[2 * BUFE];

    const bool second = (int)blockIdx.x >= o1.nblk;
    const GemmOp& o = second ? o2 : o1;
    int bidx = blockIdx.x - (second ? o1.nblk : 0);

    const int tilesN = o.N >> 7;
    const int tilesM = o.M >> 7;
    const int tiles  = tilesM * tilesN;
    const int z = bidx / tiles;
    const int t = bidx - z * tiles;
    const int zb = z / o.zdiv, zh = z - zb * o.zdiv;

    int tm, tn;
    if ((tilesM & 7) == 0) {
        const int xcd = t & 7, idx = t >> 3;
        const int mg  = tilesM >> 3;
        tm = ((idx % mg) << 3) | xcd;
        tn = idx / mg;
    } else {
        tm = t / tilesN;
        tn = t - tm * tilesN;
    }
    const int m0 = tm << 7, n0 = tn << 7;

    const u16* Ab = o.A + (long)zb * o.sA1 + (long)zh * o.sA2;
    const u16* Bb = o.B + (long)zb * o.sB1 + (long)zh * o.sB2;
    u16*   Cb  = o.C  ? o.C  + (long)zb * o.sC1 + (long)zh * o.sC2 : nullptr;
    float* Cfb = o.Cf ? o.Cf + (long)zb * o.sC1 + (long)zh * o.sC2 : nullptr;

    const int tid  = threadIdx.x;
    const int lane = tid & 63;
    const int wave = tid >> 6;
    const int wm = (wave & 1) << 6, wn = (wave >> 1) << 6;
    const int quad = lane >> 4, l16 = lane & 15;

    f32x4 acc[4][4];
#pragma unroll
    for (int i = 0; i < 4; i++)
#pragma unroll
        for (int j = 0; j < 4; j++) acc[i][j] = (f32x4){0.f, 0.f, 0.f, 0.f};

    const int lrA = (wave << 5) + (lane >> 2);
    const int lc  = (((lane & 3) ^ ((lane >> 3) & 3)) << 3);
    const u16* gA0 = Ab + (long)(m0 + lrA) * o.lda + lc;
    const u16* gA1 = Ab + (long)(m0 + lrA + 16) * o.lda + lc;
    const u16* gB0 = Bb + (long)(n0 + lrA) * o.ldb + lc;
    const u16* gB1 = Bb + (long)(n0 + lrA + 16) * o.ldb + lc;
    u16* lA0 = As + ((wave << 5) +  0) * 32;
    u16* lA1 = As + ((wave << 5) + 16) * 32;
    u16* lB0 = Bs + ((wave << 5) +  0) * 32;
    u16* lB1 = Bs + ((wave << 5) + 16) * 32;

    auto STAGE = [&](int bi, int k0) {
        llds16(gA0 + k0, lA0 + bi * BUFE);
        llds16(gA1 + k0, lA1 + bi * BUFE);
        llds16(gB0 + k0, lB0 + bi * BUFE);
        llds16(gB1 + k0, lB1 + bi * BUFE);
    };
    const int cadj = ((l16 >> 1) & 3) << 3;
    auto COMPUTE = [&](int bi) {
        const u16* Ac = As + bi * BUFE;
        const u16* Bc = Bs + bi * BUFE;
        bf16x8 af[4], bfr[4];
#pragma unroll
        for (int t2 = 0; t2 < 4; t2++)
            af[t2] = *(const bf16x8*)(Ac + (wm + t2 * 16 + l16) * 32
                                         + ((quad * 8) ^ cadj));
#pragma unroll
        for (int t2 = 0; t2 < 4; t2++)
            bfr[t2] = *(const bf16x8*)(Bc + (wn + t2 * 16 + l16) * 32
                                          + ((quad * 8) ^ cadj));
#pragma unroll
        for (int i = 0; i < 4; i++)
#pragma unroll
            for (int j = 0; j < 4; j++)
                acc[i][j] = __builtin_amdgcn_mfma_f32_16x16x32_bf16(
                    bfr[j], af[i], acc[i][j], 0, 0, 0);
    };

    const int K = o.K;
    STAGE(0, 0);
    __syncthreads();
    int cur = 0;
    for (int k0 = 0; k0 < K; k0 += 32) {
        const int nxt = cur ^ 1;
        if (k0 + 32 < K) STAGE(nxt, k0 + 32);
        COMPUTE(cur);
        __syncthreads();
        cur = nxt;
    }

#pragma unroll
    for (int i = 0; i < 4; i++) {
        const long row = m0 + wm + i * 16 + l16;
#pragma unroll
        for (int j = 0; j < 4; j++) {
            const int col = n0 + wn + j * 16 + quad * 4;
            store_frag(o, Cb, Cfb, row, col, acc[i][j]);
        }
    }
}

// ---------------------------------------------------------------------------
// Flash attention: O = softmax(scale*Q K^T + mask) V, head dim 64, L = 512.
// grid (bh, qt=4): 128 q-rows per block; 4 waves each owning 32 q-rows
// (2 sub-tiles of 16) -- every K/V LDS read feeds 2 MFMAs.  Swapped-operand
// S^T = mfma(K,Q); in-register softmax (exp2, cvt_pk); zero-shuffle PV via
// key-permutation sigma; T14 async-STAGE.
// ---------------------------------------------------------------------------
__global__ __launch_bounds__(256, 2) void flash_kernel(
    const u16* __restrict__ Q, const u16* __restrict__ K,
    const u16* __restrict__ VT, u16* __restrict__ O,
    const float* __restrict__ mask, int causal, int ldq, int ldk)
{
    __shared__ __align__(16) u16 Ks[128 * 72];    // keys x dims, pad 64->72
    __shared__ __align__(16) u16 Vs[64 * 136];    // dims x keys, pad 128->136
    const int tid  = threadIdx.x;
    const int wave = tid >> 6, lane = tid & 63;
    const int quad = lane >> 4, l16 = lane & 15;
    const int bh = blockIdx.x, qt = blockIdx.y, b = bh >> 4, h = bh & 15;
    const int qbase = qt * 128 + wave * 32;
    const int qrow0 = qbase + l16;
    const int qrow1 = qbase + 16 + l16;

    const u16* qp0 = Q + ((long)b * LTOK + qrow0) * ldq + h * 64 + quad * 8;
    const u16* qp1 = qp0 + (long)16 * ldq;
    bf16x8 aq00 = *(const bf16x8*)(qp0);
    bf16x8 aq01 = *(const bf16x8*)(qp0 + 32);
    bf16x8 aq10 = *(const bf16x8*)(qp1);
    bf16x8 aq11 = *(const bf16x8*)(qp1 + 32);

    f32x4 oacc0[4], oacc1[4];
#pragma unroll
    for (int jd = 0; jd < 4; jd++) {
        oacc0[jd] = (f32x4){0.f, 0.f, 0.f, 0.f};
        oacc1[jd] = (f32x4){0.f, 0.f, 0.f, 0.f};
    }
    float m0_ = -3.0e38f, m1_ = -3.0e38f;
    float l0_ = 0.f, l1_ = 0.f;

    const int krow = tid >> 3,       kcol = (tid & 7) << 3;
    const int vrow = tid >> 2,       vcol = (tid & 3) << 3;
    const u16* gK = K + ((long)b * LTOK + krow) * ldk + h * 64 + kcol;
    const u16* gV = VT + ((long)bh * 64 + vrow) * LTOK + vcol;

    const float C1    = 0.125f * 1.44269504088896340736f;
    const float NEGL2 = -10000.0f * 1.44269504088896340736f;

    const int nkt = causal ? (qt + 1) : (LTOK >> 7);

    u16x8 KR[4], VR[4];
#pragma unroll
    for (int i = 0; i < 4; i++) KR[i] = *(const u16x8*)(gK + (long)(i * 32) * ldk);
#pragma unroll
    for (int i = 0; i < 4; i++) VR[i] = *(const u16x8*)(gV + i * 32);
#pragma unroll
    for (int i = 0; i < 4; i++)
        *(u16x8*)(Ks + (i * 32 + krow) * 72 + kcol) = KR[i];
#pragma unroll
    for (int i = 0; i < 4; i++)
        *(u16x8*)(Vs + vrow * 136 + i * 32 + vcol) = VR[i];
    __syncthreads();

    for (int kt = 0; kt < nkt; kt++) {
        const int k0 = kt << 7;
        const bool more = (kt + 1 < nkt);

        if (more) {
            const int kn = k0 + 128;
#pragma unroll
            for (int i = 0; i < 4; i++)
                KR[i] = *(const u16x8*)(gK + (long)(kn + i * 32) * ldk);
#pragma unroll
            for (int i = 0; i < 4; i++)
                VR[i] = *(const u16x8*)(gV + kn + i * 32);
        }

        f32x4 s0[8], s1[8];
#pragma unroll
        for (int j = 0; j < 8; j++) {
            bf16x8 bk0 = *(const bf16x8*)(Ks + (j * 16 + l16) * 72 + quad * 8);
            bf16x8 bk1 = *(const bf16x8*)(Ks + (j * 16 + l16) * 72 + 32 + quad * 8);
            f32x4 z0 = (f32x4){0.f, 0.f, 0.f, 0.f};
            z0 = __builtin_amdgcn_mfma_f32_16x16x32_bf16(bk0, aq00, z0, 0, 0, 0);
            s0[j] = __builtin_amdgcn_mfma_f32_16x16x32_bf16(bk1, aq01, z0, 0, 0, 0);
            f32x4 z1 = (f32x4){0.f, 0.f, 0.f, 0.f};
            z1 = __builtin_amdgcn_mfma_f32_16x16x32_bf16(bk0, aq10, z1, 0, 0, 0);
            s1[j] = __builtin_amdgcn_mfma_f32_16x16x32_bf16(bk1, aq11, z1, 0, 0, 0);
        }

        float ta0 = -3.0e38f, ta1 = -3.0e38f, ta2 = -3.0e38f, ta3 = -3.0e38f;
        float tb0 = -3.0e38f, tb1 = -3.0e38f, tb2 = -3.0e38f, tb3 = -3.0e38f;
#pragma unroll
        for (int j = 0; j < 8; j++) {
            if (causal) {
                f32x4 m4 = *(const f32x4*)(mask + (long)b * LTOK + k0 + j * 16 + quad * 4);
#pragma unroll
                for (int r = 0; r < 4; r++) {
                    int key = k0 + j * 16 + quad * 4 + r;
                    float adm = fmaf(m4[r], -NEGL2, NEGL2);
                    s0[j][r] = fmaf(s0[j][r], C1, (key <= qrow0) ? adm : NEGL2);
                    s1[j][r] = fmaf(s1[j][r], C1, (key <= qrow1) ? adm : NEGL2);
                }
            } else {
#pragma unroll
                for (int r = 0; r < 4; r++) { s0[j][r] *= C1; s1[j][r] *= C1; }
            }
            ta0 = fmaxf(ta0, s0[j][0]); ta1 = fmaxf(ta1, s0[j][1]);
            ta2 = fmaxf(ta2, s0[j][2]); ta3 = fmaxf(ta3, s0[j][3]);
            tb0 = fmaxf(tb0, s1[j][0]); tb1 = fmaxf(tb1, s1[j][1]);
            tb2 = fmaxf(tb2, s1[j][2]); tb3 = fmaxf(tb3, s1[j][3]);
        }
        float tmax0 = fmaxf(fmaxf(ta0, ta1), fmaxf(ta2, ta3));
        float tmax1 = fmaxf(fmaxf(tb0, tb1), fmaxf(tb2, tb3));
        tmax0 = fmaxf(tmax0, __shfl_xor(tmax0, 16));
        tmax0 = fmaxf(tmax0, __shfl_xor(tmax0, 32));
        tmax1 = fmaxf(tmax1, __shfl_xor(tmax1, 16));
        tmax1 = fmaxf(tmax1, __shfl_xor(tmax1, 32));

        float mn0 = fmaxf(m0_, tmax0);
        float mn1 = fmaxf(m1_, tmax1);
        float al0 = __builtin_amdgcn_exp2f(m0_ - mn0);
        float al1 = __builtin_amdgcn_exp2f(m1_ - mn1);
        m0_ = mn0; m1_ = mn1;

        unsigned pk0[8][2], pk1[8][2];
        float ra0 = 0.f, ra1 = 0.f, ra2 = 0.f, ra3 = 0.f;
#pragma unroll
        for (int j = 0; j < 8; j++) {
            float p0 = __builtin_amdgcn_exp2f(s0[j][0] - mn0);
            float p1 = __builtin_amdgcn_exp2f(s0[j][1] - mn0);
            float p2 = __builtin_amdgcn_exp2f(s0[j][2] - mn0);
            float p3 = __builtin_amdgcn_exp2f(s0[j][3] - mn0);
            ra0 += p0; ra1 += p1; ra2 += p2; ra3 += p3;
            asm("v_cvt_pk_bf16_f32 %0, %1, %2" : "=v"(pk0[j][0]) : "v"(p0), "v"(p1));
            asm("v_cvt_pk_bf16_f32 %0, %1, %2" : "=v"(pk0[j][1]) : "v"(p2), "v"(p3));
        }
        float rsum0 = (ra0 + ra1) + (ra2 + ra3);
        float rb0 = 0.f, rb1 = 0.f, rb2 = 0.f, rb3 = 0.f;
#pragma unroll
        for (int j = 0; j < 8; j++) {
            float p0 = __builtin_amdgcn_exp2f(s1[j][0] - mn1);
            float p1 = __builtin_amdgcn_exp2f(s1[j][1] - mn1);
            float p2 = __builtin_amdgcn_exp2f(s1[j][2] - mn1);
            float p3 = __builtin_amdgcn_exp2f(s1[j][3] - mn1);
            rb0 += p0; rb1 += p1; rb2 += p2; rb3 += p3;
            asm("v_cvt_pk_bf16_f32 %0, %1, %2" : "=v"(pk1[j][0]) : "v"(p0), "v"(p1));
            asm("v_cvt_pk_bf16_f32 %0, %1, %2" : "=v"(pk1[j][1]) : "v"(p2), "v"(p3));
        }
        float rsum1 = (rb0 + rb1) + (rb2 + rb3);
        rsum0 += __shfl_xor(rsum0, 16);
        rsum0 += __shfl_xor(rsum0, 32);
        rsum1 += __shfl_xor(rsum1, 16);
        rsum1 += __shfl_xor(rsum1, 32);
        l0_ = l0_ * al0 + rsum0;
        l1_ = l1_ * al1 + rsum1;

#pragma unroll
        for (int jd = 0; jd < 4; jd++) { oacc0[jd] *= al0; oacc1[jd] *= al1; }

#pragma unroll
        for (int kk = 0; kk < 4; kk++) {
            unsigned wv0[4] = { pk0[2 * kk][0], pk0[2 * kk][1],
                                pk0[2 * kk + 1][0], pk0[2 * kk + 1][1] };
            unsigned wv1[4] = { pk1[2 * kk][0], pk1[2 * kk][1],
                                pk1[2 * kk + 1][0], pk1[2 * kk + 1][1] };
            bf16x8 bp0; __builtin_memcpy(&bp0, wv0, 16);
            bf16x8 bp1; __builtin_memcpy(&bp1, wv1, 16);
#pragma unroll
            for (int jd = 0; jd < 4; jd++) {
                const u16* vb = Vs + (jd * 16 + l16) * 136 + kk * 32 + quad * 4;
                u16 va[8];
                *(u16x4*)(va)     = *(const u16x4*)(vb);
                *(u16x4*)(va + 4) = *(const u16x4*)(vb + 16);
                bf16x8 av; __builtin_memcpy(&av, va, 16);
                oacc0[jd] = __builtin_amdgcn_mfma_f32_16x16x32_bf16(av, bp0, oacc0[jd], 0, 0, 0);
                oacc1[jd] = __builtin_amdgcn_mfma_f32_16x16x32_bf16(av, bp1, oacc1[jd], 0, 0, 0);
            }
        }

        if (more) {
            __syncthreads();
#pragma unroll
            for (int i = 0; i < 4; i++)
                *(u16x8*)(Ks + (i * 32 + krow) * 72 + kcol) = KR[i];
#pragma unroll
            for (int i = 0; i < 4; i++)
                *(u16x8*)(Vs + vrow * 136 + i * 32 + vcol) = VR[i];
            __syncthreads();
        }
    }

    float li0 = 1.f / l0_;
    float li1 = 1.f / l1_;
    long obase0 = ((long)b * LTOK + qrow0) * DDIM + h * 64;
    long obase1 = obase0 + (long)16 * DDIM;
#pragma unroll
    for (int jd = 0; jd < 4; jd++) {
        u16x4 ov0, ov1;
#pragma unroll
        for (int r = 0; r < 4; r++) {
            ov0[r] = f2bf(oacc0[jd][r] * li0);
            ov1[r] = f2bf(oacc1[jd][r] * li1);
        }
        *(u16x4*)(O + obase0 + jd * 16 + quad * 4) = ov0;
        *(u16x4*)(O + obase1 + jd * 16 + quad * 4) = ov1;
    }
}

// out = LayerNorm(a + b) * g + beta.  a: bf16.  b: bf16 unless b32 (fp32).
__global__ __launch_bounds__(256) void add_ln_kernel(
    const u16* __restrict__ a, const u16* __restrict__ b,
    const float* __restrict__ b32,
    const float* __restrict__ g, const float* __restrict__ bt,
    u16* __restrict__ o, float* __restrict__ of)
{
    long row = blockIdx.x;
    int tid = threadIdx.x;
    __shared__ float red[4];
    const u16* ar = a + row * DDIM;
    float xv[4]; float s = 0.f;
#pragma unroll
    for (int i = 0; i < 4; i++) {
        int c = tid + 256 * i;
        float sum = bf2f(ar[c]) + (b32 ? b32[row * DDIM + c] : bf2f(b[row * DDIM + c]));
        xv[i] = fminf(fmaxf(sum, -1.0e18f), 1.0e18f);
        s += xv[i];
    }
#pragma unroll
    for (int ofs = 32; ofs >= 1; ofs >>= 1) s += __shfl_xor(s, ofs);
    int wave = tid >> 6, lane = tid & 63;
    if (lane == 0) red[wave] = s;
    __syncthreads();
    float mu = (red[0] + red[1] + red[2] + red[3]) * (1.f / 1024.f);
    __syncthreads();
    float v = 0.f;
#pragma unroll
    for (int i = 0; i < 4; i++) { float d = xv[i] - mu; v += d * d; }
#pragma unroll
    for (int ofs = 32; ofs >= 1; ofs >>= 1) v += __shfl_xor(v, ofs);
    if (lane == 0) red[wave] = v;
    __syncthreads();
    float var = (red[0] + red[1] + red[2] + red[3]) * (1.f / 1024.f);
    float inv = rsqrtf(var + 1e-6f);
#pragma unroll
    for (int i = 0; i < 4; i++) {
        int c = tid + 256 * i;
        float r = (xv[i] - mu) * inv * g[c] + bt[c];
        if (of) of[row * DDIM + c] = r;
        else    o [row * DDIM + c] = f2bf(r);
    }
}

// fp32 -> bf16 conversion, 8 elements/thread, two tensors in one launch.
__global__ __launch_bounds__(256) void cvt2_kernel(
    const float* __restrict__ s0, u16* __restrict__ d0,
    const float* __restrict__ s1, u16* __restrict__ d1)
{
    const float* src = blockIdx.y ? s1 : s0;
    u16* dst = blockIdx.y ? d1 : d0;
    long i = ((long)blockIdx.x * 256 + threadIdx.x) * 8;
    u16x8 o;
#pragma unroll
    for (int j = 0; j < 8; j++) o[j] = f2bf(src[i + j]);
    *(u16x8*)(dst + i) = o;
}

// Transpose+cvt the 8 fp32 weight matrices (1024x1024): WT[n][k] = bf16(W[k][n])
__global__ __launch_bounds__(256) void wt_kernel(
    const float* w0, const float* w1, const float* w2, const float* w3,
    const float* w4, const float* w5, const float* w6, const float* w7,
    u16* __restrict__ wt)
{
    const float* srcs[8] = {w0, w1, w2, w3, w4, w5, w6, w7};
    const float* w = srcs[blockIdx.z];
    u16* o = wt + (long)blockIdx.z * DDIM * DDIM;
    __shared__ u16 t[32][33];
    int tx = threadIdx.x & 31, ty = threadIdx.x >> 5;
    int c0 = blockIdx.x << 5, r0 = blockIdx.y << 5;
#pragma unroll
    for (int i = 0; i < 4; i++)
        t[ty + 8 * i][tx] = f2bf(w[(long)(r0 + ty + 8 * i) * DDIM + c0 + tx]);
    __syncthreads();
#pragma unroll
    for (int i = 0; i < 4; i++)
        o[(long)(c0 + ty + 8 * i) * DDIM + r0 + tx] = t[tx][ty + 8 * i];
}

// Concatenate up to 3 bias vectors (1024 each) into one fp32 array.
__global__ __launch_bounds__(256) void biascat_kernel(
    const float* __restrict__ b0, const float* __restrict__ b1,
    const float* __restrict__ b2, float* __restrict__ dst)
{
    int i = blockIdx.x * 256 + threadIdx.x;
    const float* s = (i < 1024) ? b0 : (i < 2048) ? b1 : b2;
    dst[i] = s[i & 1023];
}

extern "C" void kernel_launch(void* const* d_in, const int* in_sizes, int n_in,
                              void* d_out, int out_size, void* d_ws, size_t ws_size,
                              hipStream_t stream)
{
    const float* x     = (const float*)d_in[0];
    const float* dmsk  = (const float*)d_in[1];
    const float* enc   = (const float*)d_in[2];
    const float* sa_wq = (const float*)d_in[3];  const float* sa_bq = (const float*)d_in[4];
    const float* sa_wk = (const float*)d_in[5];  const float* sa_bk = (const float*)d_in[6];
    const float* sa_wv = (const float*)d_in[7];  const float* sa_bv = (const float*)d_in[8];
    const float* n1_g  = (const float*)d_in[9];  const float* n1_b  = (const float*)d_in[10];
    const float* ca_wq = (const float*)d_in[11]; const float* ca_bq = (const float*)d_in[12];
    const float* ca_wk = (const float*)d_in[13]; const float* ca_bk = (const float*)d_in[14];
    const float* ca_wv = (const float*)d_in[15]; const float* ca_bv = (const float*)d_in[16];
    const float* n2_g  = (const float*)d_in[17]; const float* n2_b  = (const float*)d_in[18];
    const float* int_w = (const float*)d_in[19]; const float* int_b = (const float*)d_in[20];
    const float* out_w = (const float*)d_in[21]; const float* out_b = (const float*)d_in[22];
    const float* out_g = (const float*)d_in[23]; const float* out_bt= (const float*)d_in[24];

    float* outp = (float*)d_out;
    float* visp = outp + (long)NBATCH * LTOK * DDIM;   // attention_vis (fp32)

    const size_t WTB  = (size_t)8 * DDIM * DDIM * 2;            // 16 MiB
    const size_t BUF1 = (size_t)LTOK * DDIM * 2;                // 1 MiB / batch
    int cb = 16;
    while (cb > 1 && WTB + (size_t)cb * 7 * BUF1 + 32768 > ws_size)
        cb >>= 1;

    char* ws = (char*)d_ws;
    size_t off = 0;
    auto alloc = [&](size_t bytes) -> u16* {
        u16* p = (u16*)(ws + off);
        off += (bytes + 255) & ~(size_t)255;
        return p;
    };
    u16* Xb  = alloc((size_t)cb * BUF1);          // Xb -> h
    u16* Eb  = alloc((size_t)cb * BUF1);          // Eb -> h2
    u16* Q3  = alloc((size_t)cb * 3 * BUF1);      // q|k|(v unused) -> CQ | CKV
    u16* Vt  = alloc((size_t)cb * BUF1);          // per-head V^T -> I
    u16* Cx  = alloc((size_t)cb * BUF1);          // attn ctx -> G
    u16* WT  = alloc(WTB);
    float* biasQKV = (float*)alloc(3072 * sizeof(float));
    float* biasKV  = (float*)alloc(2048 * sizeof(float));

    u16* Wsaq = WT + 0L * DDIM * DDIM;   // [Wsaq|Wsak|Wsav] contiguous
    u16* Wcaq = WT + 3L * DDIM * DDIM;
    u16* Wcak = WT + 4L * DDIM * DDIM;   // [Wcak|Wcav] contiguous
    u16* Wint = WT + 6L * DDIM * DDIM;
    u16* Wout = WT + 7L * DDIM * DDIM;

    auto mkop = [](const u16* A, int lda, const u16* B, int ldb,
                   u16* C, float* Cf, int ldc, int M, int N, int K,
                   const float* bias, float scale, int flags, int tile) -> GemmOp {
        GemmOp o{};
        o.A = A; o.B = B; o.C = C; o.Cf = Cf; o.bias = bias;
        o.VTp = nullptr; o.vtcol0 = 0;
        o.sA1 = 0; o.sA2 = 0; o.sB1 = 0; o.sB2 = 0; o.sC1 = 0; o.sC2 = 0;
        o.lda = lda; o.ldb = ldb; o.ldc = ldc; o.M = M; o.N = N; o.K = K;
        o.zdiv = 1; o.flags = flags; o.nblk = (M / tile) * (N / tile);
        o.scale = scale;
        return o;
    };

    auto launch1 = [&](GemmOp o1, GemmOp o2) {       // 128^2 MODE1 kernel
        gemm_bt_kernel<<<dim3(o1.nblk + o2.nblk), dim3(256), 0, stream>>>(o1, o2);
    };
    auto launch8 = [&](GemmOp o1, GemmOp o2) {       // 256^2 8-phase kernel
        gemm8_kernel<<<dim3(o1.nblk + o2.nblk), dim3(512), 0, stream>>>(o1, o2);
    };
    GemmOp nil{};   // nblk = 0

    const long SLD = (long)LTOK * DDIM;
    const long SSC = (long)LTOK * LTOK;

    // 0) weight transposes + bf16 cvt + bias packs (once per call)
    wt_kernel<<<dim3(32, 32, 8), dim3(256), 0, stream>>>(
        sa_wq, sa_wk, sa_wv, ca_wq, ca_wk, ca_wv, int_w, out_w, WT);
    biascat_kernel<<<dim3(12), dim3(256), 0, stream>>>(sa_bq, sa_bk, sa_bv, biasQKV);
    biascat_kernel<<<dim3(8),  dim3(256), 0, stream>>>(ca_bk, ca_bv, ca_bv, biasKV);

    for (int b0 = 0; b0 < NBATCH; b0 += cb) {
        const float* xc = x   + (long)b0 * SLD;
        const float* ec = enc + (long)b0 * SLD;
        const int M = cb * LTOK;
        const int Z = cb * NH;
        const int cvtg = (int)(((long)M * DDIM) / (256 * 8));

        u16* h   = Xb;
        u16* CQ  = Q3;
        u16* CKV = Q3 + (size_t)cb * LTOK * DDIM;        // cross k|v, ld 2048
        u16* I   = Vt;
        u16* G   = Cx;
        u16* h2  = Eb;

        // a) fp32 -> bf16 activation copies
        cvt2_kernel<<<dim3(cvtg, 2), dim3(256), 0, stream>>>(xc, Xb, ec, Eb);

        // 1) fused self-attn q|k|v projection: 8-phase, N=3072 (384 blocks).
        //    V-third written transposed straight to Vt.
        {
            GemmOp o = mkop(Xb, DDIM, Wsaq, DDIM, Q3, nullptr, 3 * DDIM,
                            M, 3 * DDIM, DDIM, biasQKV, 1.f, 0, 256);
            o.VTp = Vt; o.vtcol0 = 2 * DDIM;
            launch8(o, nil);
        }

        // 2) self-attention (flash, causal+padding), ctx -> Cx
        flash_kernel<<<dim3(Z, 4), dim3(256), 0, stream>>>(
            Q3, Q3 + DDIM, Vt, Cx, dmsk + (long)b0 * LTOK, 1, 3 * DDIM, 3 * DDIM);

        // 3) h = LN(ctx + x_fp32) -> h
        add_ln_kernel<<<dim3(M), dim3(256), 0, stream>>>(
            Cx, nullptr, xc, n1_g, n1_b, h, nullptr);

        // 4) MERGED cq | cross-k|v: 8-phase, 128+256 = 384 blocks.
        //    cv-third written transposed straight to Vt.
        {
            GemmOp okv = mkop(Eb, DDIM, Wcak, DDIM, CKV, nullptr, 2 * DDIM,
                              M, 2 * DDIM, DDIM, biasKV, 1.f, 0, 256);
            okv.VTp = Vt; okv.vtcol0 = DDIM;
            launch8(mkop(h, DDIM, Wcaq, DDIM, CQ, nullptr, DDIM,
                         M, DDIM, DDIM, ca_bq, 1.f, 0, 256), okv);
        }

        // 5) cross-attention (flash, no mask): ctx -> Cx
        flash_kernel<<<dim3(Z, 4), dim3(256), 0, stream>>>(
            CQ, CKV, Vt, Cx, nullptr, 0, DDIM, 2 * DDIM);

        // 6) h2 = LN(h + cactx) -> h2
        add_ln_kernel<<<dim3(M), dim3(256), 0, stream>>>(
            h, Cx, nullptr, n2_g, n2_b, h2, nullptr);

        // 7) MERGED vis | int: 128^2 kernel (768 blocks, small tiles fit grid)
        GemmOp ovis{};
        ovis.A = CQ;  ovis.lda = DDIM;     ovis.sA1 = SLD;               ovis.sA2 = 0;
        ovis.B = CKV; ovis.ldb = 2 * DDIM; ovis.sB1 = (long)LTOK * 2 * DDIM; ovis.sB2 = 0;
        ovis.C = nullptr; ovis.Cf = visp + (long)b0 * SSC;
        ovis.VTp = nullptr; ovis.vtcol0 = 0;
        ovis.ldc = LTOK; ovis.sC1 = SSC; ovis.sC2 = 0;
        ovis.M = LTOK; ovis.N = LTOK; ovis.K = DDIM; ovis.zdiv = 1;
        ovis.bias = nullptr; ovis.scale = 1.f / 128.f; ovis.flags = 0;
        ovis.nblk = (LTOK / 128) * (LTOK / 128) * cb;     // 16 * cb
        launch1(ovis,
                mkop(h2, DDIM, Wint, DDIM, I, nullptr, DDIM,
                     M, DDIM, DDIM, int_b, 1.f, 1, 128));

        // 8) G = inter @ out_w + out_b -> G (128^2 kernel, 512 blocks)
        launch1(mkop(I, DDIM, Wout, DDIM, G, nullptr, DDIM,
                     M, DDIM, DDIM, out_b, 1.f, 0, 128), nil);

        // 9) out = LN(G + inter) -> fp32 d_out
        add_ln_kernel<<<dim3(M), dim3(256), 0, stream>>>(
            G, I, nullptr, out_g, out_bt, nullptr, outp + (long)b0 * SLD);
    }
}

// Round 11
// 529.974 us; speedup vs baseline: 1.1144x; 1.1144x over previous
//
#include <hip/hip_runtime.h>
#include <hip/hip_bf16.h>
#include <math.h>

// Problem constants
#define DDIM 1024
#define NH   16
#define LTOK 512
#define NBATCH 16

typedef unsigned short u16;
typedef unsigned short u16x8 __attribute__((ext_vector_type(8)));
typedef unsigned short u16x4 __attribute__((ext_vector_type(4)));
typedef __bf16 bf16x8 __attribute__((ext_vector_type(8)));
typedef float f32x4 __attribute__((ext_vector_type(4)));

typedef __attribute__((address_space(1))) void as1_void;
typedef __attribute__((address_space(3))) void as3_void;

__device__ __forceinline__ void llds16(const u16* g, u16* l) {
    // async 16B global->LDS DMA; LDS dest = wave-uniform base + lane*16B
    __builtin_amdgcn_global_load_lds((as1_void*)g, (as3_void*)l, 16, 0, 0);
}

__device__ __forceinline__ float bf2f(u16 u) {
    unsigned v = ((unsigned)u) << 16;
    float f; __builtin_memcpy(&f, &v, 4); return f;
}
__device__ __forceinline__ u16 f2bf(float f) {
    unsigned u; __builtin_memcpy(&u, &f, 4);
    u += 0x7fffu + ((u >> 16) & 1u);   // RNE
    return (u16)(u >> 16);
}

// One GEMM operand set:  C = act(scale*(A@B^T)+bias).  M,N multiples of 128,
// K multiple of 32.  nblk = (M/128)*(N/128)*Z.
// If VTp != nullptr, output columns >= vtcol0 are per-head V projections and
// are written TRANSPOSED to VTp[((row/512)*NH + h)*64 + dd][row%512].
struct GemmOp {
    const u16* A; const u16* B; u16* C; float* Cf; const float* bias;
    u16* VTp;
    long sA1, sA2, sB1, sB2, sC1, sC2;
    int lda, ldb, ldc, M, N, K, zdiv, flags, nblk, vtcol0;
    float scale;
};

// Shared epilogue fragment-store (C^T convention: lane holds 4 consecutive
// output columns per fragment; V-column tiles redirect transposed to VT).
__device__ __forceinline__ void store_frag(
    const GemmOp& o, u16* Cb, float* Cfb, long row, int col, f32x4 a)
{
    f32x4 bv = o.bias ? *(const f32x4*)(o.bias + col)
                      : (f32x4){0.f, 0.f, 0.f, 0.f};
    f32x4 v4;
#pragma unroll
    for (int r = 0; r < 4; r++) {
        float v = a[r] * o.scale + bv[r];
        if (o.flags & 1)
            v = 0.5f * v * (1.f + erff(v * 0.70710678118654752f));
        v4[r] = v;
    }
    if (o.VTp && col >= o.vtcol0) {
        const int dv  = col - o.vtcol0;          // head h = dv>>6
        const long bh = (row >> 9) * NH + (dv >> 6);
        const int tok = (int)(row & (LTOK - 1));
        u16* vp = o.VTp + (bh * 64 + (dv & 63)) * LTOK + tok;
#pragma unroll
        for (int r = 0; r < 4; r++)
            vp[(long)r * LTOK] = f2bf(v4[r]);
    } else if (Cfb) {
        *(f32x4*)(Cfb + row * o.ldc + col) = v4;
    } else {
        u16x4 ov;
#pragma unroll
        for (int r = 0; r < 4; r++) ov[r] = f2bf(v4[r]);
        *(u16x4*)(Cb + row * o.ldc + col) = ov;
    }
}

// ---------------------------------------------------------------------------
// Dual-op 128x128 MFMA GEMM -- 2-phase double-buffer (1 barrier/K-step,
// 32KB LDS, ~5 blocks/CU), the proven r9 configuration (~606 TF, 85us at
// the fused-QKV shape).  [r10 lesson: the coarse 8-phase 256^2 rewrite
// regressed to 115us -- 1 block/CU + 25% grid tail + no fine interleave
// (m196); the verified plateau is THIS structure.]
// XOR swizzle (r9, T2/rule#21): staging source col and read col XORed with
// a row-derived term -> bank-conflict-free (measured 0 conflicts).
// C^T epilogue via mfma operand swap -> vectorized stores; V-column tiles
// redirect transposed to VT (kills vtrans kernels).  XCD swizzle (T1).
// ---------------------------------------------------------------------------
__global__ __launch_bounds__(256) void gemm_bt_kernel(GemmOp o1, GemmOp o2)
{
    constexpr int BUFE = 128 * 32;
    __shared__ __align__(16) u16 As[2 * BUFE];
    __shared__ __align__(16) u16 Bs[2 * BUFE];

    const bool second = (int)blockIdx.x >= o1.nblk;
    const GemmOp& o = second ? o2 : o1;
    int bidx = blockIdx.x - (second ? o1.nblk : 0);

    const int tilesN = o.N >> 7;
    const int tilesM = o.M >> 7;
    const int tiles  = tilesM * tilesN;
    const int z = bidx / tiles;
    const int t = bidx - z * tiles;
    const int zb = z / o.zdiv, zh = z - zb * o.zdiv;

    int tm, tn;
    if ((tilesM & 7) == 0) {
        const int xcd = t & 7, idx = t >> 3;
        const int mg  = tilesM >> 3;
        tm = ((idx % mg) << 3) | xcd;
        tn = idx / mg;
    } else {
        tm = t / tilesN;
        tn = t - tm * tilesN;
    }
    const int m0 = tm << 7, n0 = tn << 7;

    const u16* Ab = o.A + (long)zb * o.sA1 + (long)zh * o.sA2;
    const u16* Bb = o.B + (long)zb * o.sB1 + (long)zh * o.sB2;
    u16*   Cb  = o.C  ? o.C  + (long)zb * o.sC1 + (long)zh * o.sC2 : nullptr;
    float* Cfb = o.Cf ? o.Cf + (long)zb * o.sC1 + (long)zh * o.sC2 : nullptr;

    const int tid  = threadIdx.x;
    const int lane = tid & 63;
    const int wave = tid >> 6;
    const int wm = (wave & 1) << 6, wn = (wave >> 1) << 6;
    const int quad = lane >> 4, l16 = lane & 15;

    f32x4 acc[4][4];
#pragma unroll
    for (int i = 0; i < 4; i++)
#pragma unroll
        for (int j = 0; j < 4; j++) acc[i][j] = (f32x4){0.f, 0.f, 0.f, 0.f};

    const int lrA = (wave << 5) + (lane >> 2);
    const int lc  = (((lane & 3) ^ ((lane >> 3) & 3)) << 3);
    const u16* gA0 = Ab + (long)(m0 + lrA) * o.lda + lc;
    const u16* gA1 = Ab + (long)(m0 + lrA + 16) * o.lda + lc;
    const u16* gB0 = Bb + (long)(n0 + lrA) * o.ldb + lc;
    const u16* gB1 = Bb + (long)(n0 + lrA + 16) * o.ldb + lc;
    u16* lA0 = As + ((wave << 5) +  0) * 32;
    u16* lA1 = As + ((wave << 5) + 16) * 32;
    u16* lB0 = Bs + ((wave << 5) +  0) * 32;
    u16* lB1 = Bs + ((wave << 5) + 16) * 32;

    auto STAGE = [&](int bi, int k0) {
        llds16(gA0 + k0, lA0 + bi * BUFE);
        llds16(gA1 + k0, lA1 + bi * BUFE);
        llds16(gB0 + k0, lB0 + bi * BUFE);
        llds16(gB1 + k0, lB1 + bi * BUFE);
    };
    const int cadj = ((l16 >> 1) & 3) << 3;
    auto COMPUTE = [&](int bi) {
        const u16* Ac = As + bi * BUFE;
        const u16* Bc = Bs + bi * BUFE;
        bf16x8 af[4], bfr[4];
#pragma unroll
        for (int t2 = 0; t2 < 4; t2++)
            af[t2] = *(const bf16x8*)(Ac + (wm + t2 * 16 + l16) * 32
                                         + ((quad * 8) ^ cadj));
#pragma unroll
        for (int t2 = 0; t2 < 4; t2++)
            bfr[t2] = *(const bf16x8*)(Bc + (wn + t2 * 16 + l16) * 32
                                          + ((quad * 8) ^ cadj));
        // operand-swapped: acc[i][j] holds C^T fragment
#pragma unroll
        for (int i = 0; i < 4; i++)
#pragma unroll
            for (int j = 0; j < 4; j++)
                acc[i][j] = __builtin_amdgcn_mfma_f32_16x16x32_bf16(
                    bfr[j], af[i], acc[i][j], 0, 0, 0);
    };

    const int K = o.K;
    STAGE(0, 0);
    __syncthreads();
    int cur = 0;
    for (int k0 = 0; k0 < K; k0 += 32) {
        const int nxt = cur ^ 1;
        if (k0 + 32 < K) STAGE(nxt, k0 + 32);
        COMPUTE(cur);
        __syncthreads();
        cur = nxt;
    }

#pragma unroll
    for (int i = 0; i < 4; i++) {
        const long row = m0 + wm + i * 16 + l16;
#pragma unroll
        for (int j = 0; j < 4; j++) {
            const int col = n0 + wn + j * 16 + quad * 4;
            store_frag(o, Cb, Cfb, row, col, acc[i][j]);
        }
    }
}

// ---------------------------------------------------------------------------
// Flash attention: O = softmax(scale*Q K^T + mask) V, head dim 64, L = 512.
// grid (bh, qt=4): 128 q-rows per block; 4 waves each owning 32 q-rows
// (2 sub-tiles of 16) -- every K/V LDS read feeds 2 MFMAs.  Swapped-operand
// S^T = mfma(K,Q); in-register softmax (exp2, cvt_pk); zero-shuffle PV via
// key-permutation sigma; T14 async-STAGE.
// ---------------------------------------------------------------------------
__global__ __launch_bounds__(256, 2) void flash_kernel(
    const u16* __restrict__ Q, const u16* __restrict__ K,
    const u16* __restrict__ VT, u16* __restrict__ O,
    const float* __restrict__ mask, int causal, int ldq, int ldk)
{
    __shared__ __align__(16) u16 Ks[128 * 72];    // keys x dims, pad 64->72
    __shared__ __align__(16) u16 Vs[64 * 136];    // dims x keys, pad 128->136
    const int tid  = threadIdx.x;
    const int wave = tid >> 6, lane = tid & 63;
    const int quad = lane >> 4, l16 = lane & 15;
    const int bh = blockIdx.x, qt = blockIdx.y, b = bh >> 4, h = bh & 15;
    const int qbase = qt * 128 + wave * 32;
    const int qrow0 = qbase + l16;
    const int qrow1 = qbase + 16 + l16;

    const u16* qp0 = Q + ((long)b * LTOK + qrow0) * ldq + h * 64 + quad * 8;
    const u16* qp1 = qp0 + (long)16 * ldq;
    bf16x8 aq00 = *(const bf16x8*)(qp0);
    bf16x8 aq01 = *(const bf16x8*)(qp0 + 32);
    bf16x8 aq10 = *(const bf16x8*)(qp1);
    bf16x8 aq11 = *(const bf16x8*)(qp1 + 32);

    f32x4 oacc0[4], oacc1[4];
#pragma unroll
    for (int jd = 0; jd < 4; jd++) {
        oacc0[jd] = (f32x4){0.f, 0.f, 0.f, 0.f};
        oacc1[jd] = (f32x4){0.f, 0.f, 0.f, 0.f};
    }
    float m0_ = -3.0e38f, m1_ = -3.0e38f;
    float l0_ = 0.f, l1_ = 0.f;

    const int krow = tid >> 3,       kcol = (tid & 7) << 3;
    const int vrow = tid >> 2,       vcol = (tid & 3) << 3;
    const u16* gK = K + ((long)b * LTOK + krow) * ldk + h * 64 + kcol;
    const u16* gV = VT + ((long)bh * 64 + vrow) * LTOK + vcol;

    const float C1    = 0.125f * 1.44269504088896340736f;
    const float NEGL2 = -10000.0f * 1.44269504088896340736f;

    const int nkt = causal ? (qt + 1) : (LTOK >> 7);

    u16x8 KR[4], VR[4];
#pragma unroll
    for (int i = 0; i < 4; i++) KR[i] = *(const u16x8*)(gK + (long)(i * 32) * ldk);
#pragma unroll
    for (int i = 0; i < 4; i++) VR[i] = *(const u16x8*)(gV + i * 32);
#pragma unroll
    for (int i = 0; i < 4; i++)
        *(u16x8*)(Ks + (i * 32 + krow) * 72 + kcol) = KR[i];
#pragma unroll
    for (int i = 0; i < 4; i++)
        *(u16x8*)(Vs + vrow * 136 + i * 32 + vcol) = VR[i];
    __syncthreads();

    for (int kt = 0; kt < nkt; kt++) {
        const int k0 = kt << 7;
        const bool more = (kt + 1 < nkt);

        if (more) {
            const int kn = k0 + 128;
#pragma unroll
            for (int i = 0; i < 4; i++)
                KR[i] = *(const u16x8*)(gK + (long)(kn + i * 32) * ldk);
#pragma unroll
            for (int i = 0; i < 4; i++)
                VR[i] = *(const u16x8*)(gV + kn + i * 32);
        }

        f32x4 s0[8], s1[8];
#pragma unroll
        for (int j = 0; j < 8; j++) {
            bf16x8 bk0 = *(const bf16x8*)(Ks + (j * 16 + l16) * 72 + quad * 8);
            bf16x8 bk1 = *(const bf16x8*)(Ks + (j * 16 + l16) * 72 + 32 + quad * 8);
            f32x4 z0 = (f32x4){0.f, 0.f, 0.f, 0.f};
            z0 = __builtin_amdgcn_mfma_f32_16x16x32_bf16(bk0, aq00, z0, 0, 0, 0);
            s0[j] = __builtin_amdgcn_mfma_f32_16x16x32_bf16(bk1, aq01, z0, 0, 0, 0);
            f32x4 z1 = (f32x4){0.f, 0.f, 0.f, 0.f};
            z1 = __builtin_amdgcn_mfma_f32_16x16x32_bf16(bk0, aq10, z1, 0, 0, 0);
            s1[j] = __builtin_amdgcn_mfma_f32_16x16x32_bf16(bk1, aq11, z1, 0, 0, 0);
        }

        float ta0 = -3.0e38f, ta1 = -3.0e38f, ta2 = -3.0e38f, ta3 = -3.0e38f;
        float tb0 = -3.0e38f, tb1 = -3.0e38f, tb2 = -3.0e38f, tb3 = -3.0e38f;
#pragma unroll
        for (int j = 0; j < 8; j++) {
            if (causal) {
                f32x4 m4 = *(const f32x4*)(mask + (long)b * LTOK + k0 + j * 16 + quad * 4);
#pragma unroll
                for (int r = 0; r < 4; r++) {
                    int key = k0 + j * 16 + quad * 4 + r;
                    float adm = fmaf(m4[r], -NEGL2, NEGL2);
                    s0[j][r] = fmaf(s0[j][r], C1, (key <= qrow0) ? adm : NEGL2);
                    s1[j][r] = fmaf(s1[j][r], C1, (key <= qrow1) ? adm : NEGL2);
                }
            } else {
#pragma unroll
                for (int r = 0; r < 4; r++) { s0[j][r] *= C1; s1[j][r] *= C1; }
            }
            ta0 = fmaxf(ta0, s0[j][0]); ta1 = fmaxf(ta1, s0[j][1]);
            ta2 = fmaxf(ta2, s0[j][2]); ta3 = fmaxf(ta3, s0[j][3]);
            tb0 = fmaxf(tb0, s1[j][0]); tb1 = fmaxf(tb1, s1[j][1]);
            tb2 = fmaxf(tb2, s1[j][2]); tb3 = fmaxf(tb3, s1[j][3]);
        }
        float tmax0 = fmaxf(fmaxf(ta0, ta1), fmaxf(ta2, ta3));
        float tmax1 = fmaxf(fmaxf(tb0, tb1), fmaxf(tb2, tb3));
        tmax0 = fmaxf(tmax0, __shfl_xor(tmax0, 16));
        tmax0 = fmaxf(tmax0, __shfl_xor(tmax0, 32));
        tmax1 = fmaxf(tmax1, __shfl_xor(tmax1, 16));
        tmax1 = fmaxf(tmax1, __shfl_xor(tmax1, 32));

        float mn0 = fmaxf(m0_, tmax0);
        float mn1 = fmaxf(m1_, tmax1);
        float al0 = __builtin_amdgcn_exp2f(m0_ - mn0);
        float al1 = __builtin_amdgcn_exp2f(m1_ - mn1);
        m0_ = mn0; m1_ = mn1;

        unsigned pk0[8][2], pk1[8][2];
        float ra0 = 0.f, ra1 = 0.f, ra2 = 0.f, ra3 = 0.f;
#pragma unroll
        for (int j = 0; j < 8; j++) {
            float p0 = __builtin_amdgcn_exp2f(s0[j][0] - mn0);
            float p1 = __builtin_amdgcn_exp2f(s0[j][1] - mn0);
            float p2 = __builtin_amdgcn_exp2f(s0[j][2] - mn0);
            float p3 = __builtin_amdgcn_exp2f(s0[j][3] - mn0);
            ra0 += p0; ra1 += p1; ra2 += p2; ra3 += p3;
            asm("v_cvt_pk_bf16_f32 %0, %1, %2" : "=v"(pk0[j][0]) : "v"(p0), "v"(p1));
            asm("v_cvt_pk_bf16_f32 %0, %1, %2" : "=v"(pk0[j][1]) : "v"(p2), "v"(p3));
        }
        float rsum0 = (ra0 + ra1) + (ra2 + ra3);
        float rb0 = 0.f, rb1 = 0.f, rb2 = 0.f, rb3 = 0.f;
#pragma unroll
        for (int j = 0; j < 8; j++) {
            float p0 = __builtin_amdgcn_exp2f(s1[j][0] - mn1);
            float p1 = __builtin_amdgcn_exp2f(s1[j][1] - mn1);
            float p2 = __builtin_amdgcn_exp2f(s1[j][2] - mn1);
            float p3 = __builtin_amdgcn_exp2f(s1[j][3] - mn1);
            rb0 += p0; rb1 += p1; rb2 += p2; rb3 += p3;
            asm("v_cvt_pk_bf16_f32 %0, %1, %2" : "=v"(pk1[j][0]) : "v"(p0), "v"(p1));
            asm("v_cvt_pk_bf16_f32 %0, %1, %2" : "=v"(pk1[j][1]) : "v"(p2), "v"(p3));
        }
        float rsum1 = (rb0 + rb1) + (rb2 + rb3);
        rsum0 += __shfl_xor(rsum0, 16);
        rsum0 += __shfl_xor(rsum0, 32);
        rsum1 += __shfl_xor(rsum1, 16);
        rsum1 += __shfl_xor(rsum1, 32);
        l0_ = l0_ * al0 + rsum0;
        l1_ = l1_ * al1 + rsum1;

#pragma unroll
        for (int jd = 0; jd < 4; jd++) { oacc0[jd] *= al0; oacc1[jd] *= al1; }

#pragma unroll
        for (int kk = 0; kk < 4; kk++) {
            unsigned wv0[4] = { pk0[2 * kk][0], pk0[2 * kk][1],
                                pk0[2 * kk + 1][0], pk0[2 * kk + 1][1] };
            unsigned wv1[4] = { pk1[2 * kk][0], pk1[2 * kk][1],
                                pk1[2 * kk + 1][0], pk1[2 * kk + 1][1] };
            bf16x8 bp0; __builtin_memcpy(&bp0, wv0, 16);
            bf16x8 bp1; __builtin_memcpy(&bp1, wv1, 16);
#pragma unroll
            for (int jd = 0; jd < 4; jd++) {
                const u16* vb = Vs + (jd * 16 + l16) * 136 + kk * 32 + quad * 4;
                u16 va[8];
                *(u16x4*)(va)     = *(const u16x4*)(vb);
                *(u16x4*)(va + 4) = *(const u16x4*)(vb + 16);
                bf16x8 av; __builtin_memcpy(&av, va, 16);
                oacc0[jd] = __builtin_amdgcn_mfma_f32_16x16x32_bf16(av, bp0, oacc0[jd], 0, 0, 0);
                oacc1[jd] = __builtin_amdgcn_mfma_f32_16x16x32_bf16(av, bp1, oacc1[jd], 0, 0, 0);
            }
        }

        if (more) {
            __syncthreads();
#pragma unroll
            for (int i = 0; i < 4; i++)
                *(u16x8*)(Ks + (i * 32 + krow) * 72 + kcol) = KR[i];
#pragma unroll
            for (int i = 0; i < 4; i++)
                *(u16x8*)(Vs + vrow * 136 + i * 32 + vcol) = VR[i];
            __syncthreads();
        }
    }

    float li0 = 1.f / l0_;
    float li1 = 1.f / l1_;
    long obase0 = ((long)b * LTOK + qrow0) * DDIM + h * 64;
    long obase1 = obase0 + (long)16 * DDIM;
#pragma unroll
    for (int jd = 0; jd < 4; jd++) {
        u16x4 ov0, ov1;
#pragma unroll
        for (int r = 0; r < 4; r++) {
            ov0[r] = f2bf(oacc0[jd][r] * li0);
            ov1[r] = f2bf(oacc1[jd][r] * li1);
        }
        *(u16x4*)(O + obase0 + jd * 16 + quad * 4) = ov0;
        *(u16x4*)(O + obase1 + jd * 16 + quad * 4) = ov1;
    }
}

// out = LayerNorm(a + b) * g + beta.  a: bf16.  b: bf16 unless b32 (fp32).
// Output: bf16 (o) unless of != nullptr (fp32).  Row length 1024.
// ONE WAVE PER ROW (16 elems/lane): pure shuffle reduction, zero barriers,
// zero LDS -- replaces the 3-__syncthreads block-per-row version.
// 4 rows per 256-thread block; grid = rows/4.
__global__ __launch_bounds__(256) void add_ln_kernel(
    const u16* __restrict__ a, const u16* __restrict__ b,
    const float* __restrict__ b32,
    const float* __restrict__ g, const float* __restrict__ bt,
    u16* __restrict__ o, float* __restrict__ of)
{
    const int wave = threadIdx.x >> 6, lane = threadIdx.x & 63;
    const long row = (long)blockIdx.x * 4 + wave;
    const int c0 = lane << 4;                      // 16 elems per lane

    const u16* ar = a + row * DDIM + c0;
    u16x8 a0 = *(const u16x8*)(ar);
    u16x8 a1 = *(const u16x8*)(ar + 8);

    float xv[16];
    if (b32) {
        const float* br = b32 + row * DDIM + c0;
        f32x4 b4[4];
#pragma unroll
        for (int q = 0; q < 4; q++) b4[q] = *(const f32x4*)(br + q * 4);
#pragma unroll
        for (int j = 0; j < 16; j++) {
            float av = bf2f(j < 8 ? a0[j] : a1[j - 8]);
            xv[j] = av + b4[j >> 2][j & 3];
        }
    } else {
        const u16* br = b + row * DDIM + c0;
        u16x8 b0 = *(const u16x8*)(br);
        u16x8 b1 = *(const u16x8*)(br + 8);
#pragma unroll
        for (int j = 0; j < 16; j++) {
            float av = bf2f(j < 8 ? a0[j] : a1[j - 8]);
            float bv = bf2f(j < 8 ? b0[j] : b1[j - 8]);
            xv[j] = av + bv;
        }
    }
    float s = 0.f;
#pragma unroll
    for (int j = 0; j < 16; j++) {
        xv[j] = fminf(fmaxf(xv[j], -1.0e18f), 1.0e18f);
        s += xv[j];
    }
#pragma unroll
    for (int ofs = 32; ofs >= 1; ofs >>= 1) s += __shfl_xor(s, ofs);
    float mu = s * (1.f / 1024.f);
    float v = 0.f;
#pragma unroll
    for (int j = 0; j < 16; j++) { float d = xv[j] - mu; v += d * d; }
#pragma unroll
    for (int ofs = 32; ofs >= 1; ofs >>= 1) v += __shfl_xor(v, ofs);
    float inv = rsqrtf(v * (1.f / 1024.f) + 1e-6f);

    f32x4 g4[4], t4[4];
#pragma unroll
    for (int q = 0; q < 4; q++) {
        g4[q] = *(const f32x4*)(g + c0 + q * 4);
        t4[q] = *(const f32x4*)(bt + c0 + q * 4);
    }
    if (of) {
        float* orow = of + row * DDIM + c0;
#pragma unroll
        for (int q = 0; q < 4; q++) {
            f32x4 r4;
#pragma unroll
            for (int e = 0; e < 4; e++)
                r4[e] = (xv[q * 4 + e] - mu) * inv * g4[q][e] + t4[q][e];
            *(f32x4*)(orow + q * 4) = r4;
        }
    } else {
        u16x8 r0, r1;
#pragma unroll
        for (int j = 0; j < 16; j++) {
            u16 rv = f2bf((xv[j] - mu) * inv * g4[j >> 2][j & 3] + t4[j >> 2][j & 3]);
            if (j < 8) r0[j] = rv; else r1[j - 8] = rv;
        }
        u16* orow = o + row * DDIM + c0;
        *(u16x8*)(orow)     = r0;
        *(u16x8*)(orow + 8) = r1;
    }
}

// fp32 -> bf16 conversion, 8 elements/thread, two tensors in one launch.
__global__ __launch_bounds__(256) void cvt2_kernel(
    const float* __restrict__ s0, u16* __restrict__ d0,
    const float* __restrict__ s1, u16* __restrict__ d1)
{
    const float* src = blockIdx.y ? s1 : s0;
    u16* dst = blockIdx.y ? d1 : d0;
    long i = ((long)blockIdx.x * 256 + threadIdx.x) * 8;
    u16x8 o;
#pragma unroll
    for (int j = 0; j < 8; j++) o[j] = f2bf(src[i + j]);
    *(u16x8*)(dst + i) = o;
}

// Transpose+cvt the 8 fp32 weight matrices (1024x1024): WT[n][k] = bf16(W[k][n])
__global__ __launch_bounds__(256) void wt_kernel(
    const float* w0, const float* w1, const float* w2, const float* w3,
    const float* w4, const float* w5, const float* w6, const float* w7,
    u16* __restrict__ wt)
{
    const float* srcs[8] = {w0, w1, w2, w3, w4, w5, w6, w7};
    const float* w = srcs[blockIdx.z];
    u16* o = wt + (long)blockIdx.z * DDIM * DDIM;
    __shared__ u16 t[32][33];
    int tx = threadIdx.x & 31, ty = threadIdx.x >> 5;
    int c0 = blockIdx.x << 5, r0 = blockIdx.y << 5;
#pragma unroll
    for (int i = 0; i < 4; i++)
        t[ty + 8 * i][tx] = f2bf(w[(long)(r0 + ty + 8 * i) * DDIM + c0 + tx]);
    __syncthreads();
#pragma unroll
    for (int i = 0; i < 4; i++)
        o[(long)(c0 + ty + 8 * i) * DDIM + r0 + tx] = t[tx][ty + 8 * i];
}

// Pack both concatenated bias arrays in one launch:
//   dQKV[0:3072] = [bq|bk|bv], dKV[0:2048] = [ck|cv].  Grid = 20 blocks.
__global__ __launch_bounds__(256) void biascat2_kernel(
    const float* __restrict__ q, const float* __restrict__ k,
    const float* __restrict__ v, const float* __restrict__ ck,
    const float* __restrict__ cv, float* __restrict__ dQKV,
    float* __restrict__ dKV)
{
    int i = blockIdx.x * 256 + threadIdx.x;
    if (i < 3072) {
        const float* s = (i < 1024) ? q : (i < 2048) ? k : v;
        dQKV[i] = s[i & 1023];
    } else {
        int j = i - 3072;
        dKV[j] = (j < 1024 ? ck : cv)[j & 1023];
    }
}

extern "C" void kernel_launch(void* const* d_in, const int* in_sizes, int n_in,
                              void* d_out, int out_size, void* d_ws, size_t ws_size,
                              hipStream_t stream)
{
    const float* x     = (const float*)d_in[0];
    const float* dmsk  = (const float*)d_in[1];
    const float* enc   = (const float*)d_in[2];
    const float* sa_wq = (const float*)d_in[3];  const float* sa_bq = (const float*)d_in[4];
    const float* sa_wk = (const float*)d_in[5];  const float* sa_bk = (const float*)d_in[6];
    const float* sa_wv = (const float*)d_in[7];  const float* sa_bv = (const float*)d_in[8];
    const float* n1_g  = (const float*)d_in[9];  const float* n1_b  = (const float*)d_in[10];
    const float* ca_wq = (const float*)d_in[11]; const float* ca_bq = (const float*)d_in[12];
    const float* ca_wk = (const float*)d_in[13]; const float* ca_bk = (const float*)d_in[14];
    const float* ca_wv = (const float*)d_in[15]; const float* ca_bv = (const float*)d_in[16];
    const float* n2_g  = (const float*)d_in[17]; const float* n2_b  = (const float*)d_in[18];
    const float* int_w = (const float*)d_in[19]; const float* int_b = (const float*)d_in[20];
    const float* out_w = (const float*)d_in[21]; const float* out_b = (const float*)d_in[22];
    const float* out_g = (const float*)d_in[23]; const float* out_bt= (const float*)d_in[24];

    float* outp = (float*)d_out;
    float* visp = outp + (long)NBATCH * LTOK * DDIM;   // attention_vis (fp32)

    const size_t WTB  = (size_t)8 * DDIM * DDIM * 2;            // 16 MiB
    const size_t BUF1 = (size_t)LTOK * DDIM * 2;                // 1 MiB / batch
    int cb = 16;
    while (cb > 1 && WTB + (size_t)cb * 7 * BUF1 + 32768 > ws_size)
        cb >>= 1;

    char* ws = (char*)d_ws;
    size_t off = 0;
    auto alloc = [&](size_t bytes) -> u16* {
        u16* p = (u16*)(ws + off);
        off += (bytes + 255) & ~(size_t)255;
        return p;
    };
    u16* Xb  = alloc((size_t)cb * BUF1);          // Xb -> h
    u16* Eb  = alloc((size_t)cb * BUF1);          // Eb -> h2
    u16* Q3  = alloc((size_t)cb * 3 * BUF1);      // q|k|(v unused) -> CQ | CKV
    u16* Vt  = alloc((size_t)cb * BUF1);          // per-head V^T -> I
    u16* Cx  = alloc((size_t)cb * BUF1);          // attn ctx -> G
    u16* WT  = alloc(WTB);
    float* biasQKV = (float*)alloc(3072 * sizeof(float));
    float* biasKV  = (float*)alloc(2048 * sizeof(float));

    u16* Wsaq = WT + 0L * DDIM * DDIM;   // [Wsaq|Wsak|Wsav] contiguous
    u16* Wcaq = WT + 3L * DDIM * DDIM;
    u16* Wcak = WT + 4L * DDIM * DDIM;   // [Wcak|Wcav] contiguous
    u16* Wint = WT + 6L * DDIM * DDIM;
    u16* Wout = WT + 7L * DDIM * DDIM;

    auto mkop = [](const u16* A, int lda, const u16* B, int ldb,
                   u16* C, float* Cf, int ldc, int M, int N, int K,
                   const float* bias, float scale, int flags) -> GemmOp {
        GemmOp o{};
        o.A = A; o.B = B; o.C = C; o.Cf = Cf; o.bias = bias;
        o.VTp = nullptr; o.vtcol0 = 0;
        o.sA1 = 0; o.sA2 = 0; o.sB1 = 0; o.sB2 = 0; o.sC1 = 0; o.sC2 = 0;
        o.lda = lda; o.ldb = ldb; o.ldc = ldc; o.M = M; o.N = N; o.K = K;
        o.zdiv = 1; o.flags = flags; o.nblk = (M / 128) * (N / 128);
        o.scale = scale;
        return o;
    };

    auto launch = [&](GemmOp o1, GemmOp o2) {
        gemm_bt_kernel<<<dim3(o1.nblk + o2.nblk), dim3(256), 0, stream>>>(o1, o2);
    };
    GemmOp nil{};   // nblk = 0

    const long SLD = (long)LTOK * DDIM;
    const long SSC = (long)LTOK * LTOK;

    // 0) weight transposes + bf16 cvt + bias packs (once per call)
    wt_kernel<<<dim3(32, 32, 8), dim3(256), 0, stream>>>(
        sa_wq, sa_wk, sa_wv, ca_wq, ca_wk, ca_wv, int_w, out_w, WT);
    biascat2_kernel<<<dim3(20), dim3(256), 0, stream>>>(
        sa_bq, sa_bk, sa_bv, ca_bk, ca_bv, biasQKV, biasKV);

    for (int b0 = 0; b0 < NBATCH; b0 += cb) {
        const float* xc = x   + (long)b0 * SLD;
        const float* ec = enc + (long)b0 * SLD;
        const int M = cb * LTOK;
        const int Z = cb * NH;
        const int cvtg = (int)(((long)M * DDIM) / (256 * 8));

        u16* h   = Xb;
        u16* CQ  = Q3;
        u16* CKV = Q3 + (size_t)cb * LTOK * DDIM;        // cross k|v, ld 2048
        u16* I   = Vt;
        u16* G   = Cx;
        u16* h2  = Eb;

        // a) fp32 -> bf16 activation copies
        cvt2_kernel<<<dim3(cvtg, 2), dim3(256), 0, stream>>>(xc, Xb, ec, Eb);

        // 1) fused self-attn q|k|v projection: N=3072 (1536 blocks).
        //    V-third written transposed straight to Vt.
        {
            GemmOp o = mkop(Xb, DDIM, Wsaq, DDIM, Q3, nullptr, 3 * DDIM,
                            M, 3 * DDIM, DDIM, biasQKV, 1.f, 0);
            o.VTp = Vt; o.vtcol0 = 2 * DDIM;
            launch(o, nil);
        }

        // 2) self-attention (flash, causal+padding), ctx -> Cx
        flash_kernel<<<dim3(Z, 4), dim3(256), 0, stream>>>(
            Q3, Q3 + DDIM, Vt, Cx, dmsk + (long)b0 * LTOK, 1, 3 * DDIM, 3 * DDIM);

        // 3) h = LN(ctx + x_fp32) -> h
        add_ln_kernel<<<dim3(M / 4), dim3(256), 0, stream>>>(
            Cx, nullptr, xc, n1_g, n1_b, h, nullptr);

        // 4) MERGED cq | cross-k|v: 1536 blocks.
        //    cv-third written transposed straight to Vt.
        {
            GemmOp okv = mkop(Eb, DDIM, Wcak, DDIM, CKV, nullptr, 2 * DDIM,
                              M, 2 * DDIM, DDIM, biasKV, 1.f, 0);
            okv.VTp = Vt; okv.vtcol0 = DDIM;
            launch(mkop(h, DDIM, Wcaq, DDIM, CQ, nullptr, DDIM,
                        M, DDIM, DDIM, ca_bq, 1.f, 0), okv);
        }

        // 5) cross-attention (flash, no mask): ctx -> Cx
        flash_kernel<<<dim3(Z, 4), dim3(256), 0, stream>>>(
            CQ, CKV, Vt, Cx, nullptr, 0, DDIM, 2 * DDIM);

        // 6) h2 = LN(h + cactx) -> h2
        add_ln_kernel<<<dim3(M / 4), dim3(256), 0, stream>>>(
            h, Cx, nullptr, n2_g, n2_b, h2, nullptr);

        // 7) MERGED vis | int: 256 + 512 = 768 blocks (3/CU).
        GemmOp ovis{};
        ovis.A = CQ;  ovis.lda = DDIM;     ovis.sA1 = SLD;               ovis.sA2 = 0;
        ovis.B = CKV; ovis.ldb = 2 * DDIM; ovis.sB1 = (long)LTOK * 2 * DDIM; ovis.sB2 = 0;
        ovis.C = nullptr; ovis.Cf = visp + (long)b0 * SSC;
        ovis.VTp = nullptr; ovis.vtcol0 = 0;
        ovis.ldc = LTOK; ovis.sC1 = SSC; ovis.sC2 = 0;
        ovis.M = LTOK; ovis.N = LTOK; ovis.K = DDIM; ovis.zdiv = 1;
        ovis.bias = nullptr; ovis.scale = 1.f / 128.f; ovis.flags = 0;
        ovis.nblk = (LTOK / 128) * (LTOK / 128) * cb;     // 16 * cb
        launch(ovis,
               mkop(h2, DDIM, Wint, DDIM, I, nullptr, DDIM,
                    M, DDIM, DDIM, int_b, 1.f, 1));

        // 8) G = inter @ out_w + out_b -> G
        launch(mkop(I, DDIM, Wout, DDIM, G, nullptr, DDIM,
                    M, DDIM, DDIM, out_b, 1.f, 0), nil);

        // 9) out = LN(G + inter) -> fp32 d_out
        add_ln_kernel<<<dim3(M / 4), dim3(256), 0, stream>>>(
            G, I, nullptr, out_g, out_bt, nullptr, outp + (long)b0 * SLD);
    }
}